// Round 15
// baseline (191.623 us; speedup 1.0000x reference)
//
#include <hip/hip_runtime.h>
#include <hip/hip_fp16.h>
#include <stdint.h>
#include <string.h>

// ContextualAttention on MI355X.
// Pipeline:
//  k_down:    x -> (bf16x3 packed F3a/F3b for Gram GEMM) + per-pixel sumsq S
//  k_mask:    mask -> 2x2 avg-pooled md
//  k_mmnorm:  md,S -> mm (valid-patch mask), ninv (1/patch-norm)
//  k_xpack:   x -> XpT[j=(a,b,c)][l=(p,q)] bf16 (deconv weights, transposed for GEMM B)
//  gemm_bt<F16,SYMM>: U(fp16) = F3a . F3b^T  (Gram; 171 upper-triangle 128^2 tiles)
//  k_patchsum:V(fp16)[hw][pq] = 9-tap diag stencil of U * ninv[pq]
//  k_fsm:     fused fuse1 + fuse2 + masked softmax -> A (bf16)
//  gemm_ap144: P(bf16) = A . XpT^T   [144x144 tiles, 9 waves, 512 blocks = 2/CU,
//              BK=64 (36 K-steps, 18 MFMA/barrier), uniform 2+2 gloads/thread]
//  k_scatter: out = parity-gather of P / 4  (4 channels/thread)

namespace {

constexpr int B_ = 4;
constexpr int H_ = 96;
constexpr int W_ = 96;
constexpr int C_ = 128;
constexpr int h_ = 48;
constexpr int L_ = 2304;   // h_*h_
constexpr int N9_ = 1152;  // 9*C_
constexpr int K3_ = 384;   // 3*C_  bf16x3 packed K
constexpr float SCALE_ = 10.0f;
constexpr float EPS_ = 1e-4f;

constexpr int OUT_F16 = 1;
constexpr int OUT_BF16 = 2;

typedef unsigned short u16;
typedef __attribute__((ext_vector_type(8))) short bfrag8;            // 8 bf16
typedef __attribute__((ext_vector_type(8))) unsigned short ushort8;  // 16B
typedef __attribute__((ext_vector_type(4))) unsigned short ushort4v; // 8B
typedef __attribute__((ext_vector_type(4))) float f32x4;
typedef __attribute__((ext_vector_type(2))) float f32x2;

__device__ __forceinline__ u16 f2bf(float f) {
  uint32_t x;
  __builtin_memcpy(&x, &f, 4);
  uint32_t lsb = (x >> 16) & 1u;
  x += 0x7fffu + lsb;
  return (u16)(x >> 16);
}
__device__ __forceinline__ float bf2f(u16 u) {
  uint32_t v = ((uint32_t)u) << 16;
  float f;
  __builtin_memcpy(&f, &v, 4);
  return f;
}
__device__ __forceinline__ u16 f2h(float f) {
  __half h = __float2half(f);
  u16 u;
  __builtin_memcpy(&u, &h, 2);
  return u;
}
__device__ __forceinline__ float h2f(u16 u) {
  __half h;
  __builtin_memcpy(&h, &u, 2);
  return __half2float(h);
}

// async global(16B/lane) -> LDS (wave-uniform base + lane*16)
__device__ __forceinline__ void gload16(const u16* g, void* l) {
  __builtin_amdgcn_global_load_lds(
      (const __attribute__((address_space(1))) void*)g,
      (__attribute__((address_space(3))) void*)l, 16, 0, 0);
}

// XCD-chunked bijective block swizzle (m204 variant, any nwg)
__device__ __forceinline__ int xcd_swz8(int orig, int nwg) {
  int q = nwg >> 3, r = nwg & 7;
  int xcd = orig & 7, pos = orig >> 3;
  return (xcd < r ? xcd * (q + 1) : r * (q + 1) + (xcd - r) * q) + pos;
}

// LDS byte-offset swizzle (involution): XOR bits[9:7] onto 16B-slot bits[6:4].
__device__ __forceinline__ uint32_t swzb(uint32_t byte) {
  return byte ^ (((byte >> 7) & 7u) << 4);
}

// ---- downscale (2x2 avg) + bf16x3 pack + per-pixel sum of squares -------
__global__ __launch_bounds__(128) void k_down(const float* __restrict__ x,
                                              u16* __restrict__ F3a,
                                              u16* __restrict__ F3b,
                                              float* __restrict__ S) {
  int blk = blockIdx.x;
  int b = blk / L_, l = blk % L_;
  int p = l / h_, q = l % h_;
  int c = threadIdx.x;
  const float* xb = x + (((size_t)b * H_ + 2 * p) * W_ + 2 * q) * C_ + c;
  float v = 0.25f * (xb[0] + xb[C_] + xb[(size_t)W_ * C_] + xb[(size_t)W_ * C_ + C_]);
  u16 hi = f2bf(v);
  u16 lo = f2bf(v - bf2f(hi));
  size_t base = ((size_t)b * L_ + l) * K3_;
  F3a[base + c] = hi; F3a[base + 128 + c] = hi; F3a[base + 256 + c] = lo;
  F3b[base + c] = hi; F3b[base + 128 + c] = lo; F3b[base + 256 + c] = hi;
  float ss = v * v;
#pragma unroll
  for (int o = 32; o >= 1; o >>= 1) ss += __shfl_xor(ss, o, 64);
  __shared__ float w2[2];
  if ((c & 63) == 0) w2[c >> 6] = ss;
  __syncthreads();
  if (c == 0) S[(size_t)b * L_ + l] = w2[0] + w2[1];
}

// ---- mask 2x2 avg-pool --------------------------------------------------
__global__ __launch_bounds__(256) void k_mask(const float* __restrict__ mask,
                                              float* __restrict__ md) {
  int i = blockIdx.x * 256 + threadIdx.x;
  int b = i / L_, l = i % L_, p = l / h_, q = l % h_;
  const float* mb = mask + ((size_t)b * H_ + 2 * p) * W_ + 2 * q;
  md[i] = 0.25f * (mb[0] + mb[1] + mb[W_] + mb[W_ + 1]);
}

// ---- valid-patch mask + 1/patch-norm ------------------------------------
__global__ __launch_bounds__(256) void k_mmnorm(const float* __restrict__ S,
                                                const float* __restrict__ md,
                                                float* __restrict__ mm,
                                                float* __restrict__ ninv) {
  int i = blockIdx.x * 256 + threadIdx.x;
  int b = i / L_, l = i % L_, p = l / h_, q = l % h_;
  float ssum = 0.f, msum = 0.f;
#pragma unroll
  for (int a = 0; a < 3; a++) {
    int rp = p - 1 + a;
#pragma unroll
    for (int bb = 0; bb < 3; bb++) {
      int rq = q - 1 + bb;
      bool ok = ((unsigned)rp < (unsigned)h_) && ((unsigned)rq < (unsigned)h_);
      int idx = ok ? (b * L_ + rp * h_ + rq) : 0;
      float sv = S[idx], mv = md[idx];
      if (ok) { ssum += sv; msum += mv; }
    }
  }
  mm[i] = (msum == 0.f) ? 1.f : 0.f;
  float n = fmaxf(sqrtf(ssum), EPS_);
  ninv[i] = 1.f / n;
}

// ---- pack deconv weights transposed: XpT[bz][j=(a,bb,c)][l=(p,q)] -------
__global__ __launch_bounds__(256) void k_xpack(const float* __restrict__ x,
                                               u16* __restrict__ XpT) {
  int lt = blockIdx.x * 32, jt = blockIdx.y * 64, bz = blockIdx.z;
  __shared__ u16 tile[32][65];
  int t = threadIdx.x;
  int jj = t & 63, lq = t >> 6;
  for (int pass = 0; pass < 8; ++pass) {
    int ll = pass * 4 + lq;
    int l = lt + ll;
    int p = l / h_, q = l % h_;
    int j = jt + jj;
    int a = j / 384, rem = j % 384, bb = rem / 128, c = rem % 128;
    int gy = 2 * p + a, gx = 2 * q + bb;
    float v = 0.f;
    if (gy < H_ && gx < W_) v = x[(((size_t)bz * H_ + gy) * W_ + gx) * C_ + c];
    tile[ll][jj] = f2bf(v);
  }
  __syncthreads();
  int lw = t & 31, jq = t >> 5;
  for (int pass = 0; pass < 8; ++pass) {
    int j2 = pass * 8 + jq;
    XpT[((size_t)bz * N9_ + jt + j2) * L_ + lt + lw] = tile[lw][j2];
  }
}

// ---- Gram MFMA GEMM (R7-proven 128^2 structure, SYMM triangle) ----------
template <int OUT, bool SYMM>
__global__ __launch_bounds__(256) void gemm_bt(const u16* __restrict__ A,
                                               const u16* __restrict__ B,
                                               void* __restrict__ Cv,
                                               int N, int Kd,
                                               size_t sA, size_t sB, size_t sC) {
  const u16* Ab = A + (size_t)blockIdx.z * sA;
  const u16* Bb = B + (size_t)blockIdx.z * sB;
  int bx, by;
  if (SYMM) {
    int wgid = xcd_swz8(blockIdx.x, gridDim.x);   // 171 tiles
    int t2 = wgid, row = 0, len = 18;
    while (t2 >= len) { t2 -= len; --len; ++row; }
    by = row;
    bx = row + t2;
  } else {
    int nwg = gridDim.x * gridDim.y;
    int orig = blockIdx.y * gridDim.x + blockIdx.x;
    int wgid = xcd_swz8(orig, nwg);
    bx = wgid % gridDim.x;
    by = wgid / gridDim.x;
  }
  int m0 = by * 128, n0 = bx * 128;

  __shared__ __align__(128) char As[2][8192];
  __shared__ __align__(128) char Bs[2][8192];
  int t = threadIdx.x;
  int lane = t & 63, wv = t >> 6, wr = wv >> 1, wc = wv & 1;
  int mrow = lane & 15, kg = lane >> 4;
  f32x4 acc[4][4];
#pragma unroll
  for (int i = 0; i < 4; i++)
#pragma unroll
    for (int j = 0; j < 4; j++) acc[i][j] = (f32x4)(0.0f);

  uint32_t d16 = (uint32_t)t * 16u;
  uint32_t sz = swzb(d16);
  int rowp = (int)(sz >> 6);        // 0..63 permuted row (64B rows)
  int kcp = (int)((sz >> 4) & 3u);  // permuted 16B chunk in row
  const u16* ga0 = Ab + (size_t)(m0 + rowp) * Kd + kcp * 8;
  const u16* ga1 = Ab + (size_t)(m0 + 64 + rowp) * Kd + kcp * 8;
  const u16* gb0 = Bb + (size_t)(n0 + rowp) * Kd + kcp * 8;
  const u16* gb1 = Bb + (size_t)(n0 + 64 + rowp) * Kd + kcp * 8;

  auto STAGE = [&](int buf, int k0) {
    gload16(ga0 + k0, As[buf] + wv * 1024);
    gload16(ga1 + k0, As[buf] + 4096 + wv * 1024);
    gload16(gb0 + k0, Bs[buf] + wv * 1024);
    gload16(gb1 + k0, Bs[buf] + 4096 + wv * 1024);
  };

  int nsteps = Kd >> 5;
  STAGE(0, 0);
  __syncthreads();
  int cur = 0;
  for (int s = 0; s < nsteps; ++s) {
    if (s + 1 < nsteps) STAGE(cur ^ 1, (s + 1) << 5);
    bfrag8 af[4], bf[4];
#pragma unroll
    for (int i = 0; i < 4; i++) {
      uint32_t byte = (uint32_t)(wr * 64 + i * 16 + mrow) * 64u + (uint32_t)kg * 16u;
      af[i] = *(const bfrag8*)(As[cur] + swzb(byte));
    }
#pragma unroll
    for (int i = 0; i < 4; i++) {
      uint32_t byte = (uint32_t)(wc * 64 + i * 16 + mrow) * 64u + (uint32_t)kg * 16u;
      bf[i] = *(const bfrag8*)(Bs[cur] + swzb(byte));
    }
#pragma unroll
    for (int i = 0; i < 4; i++)
#pragma unroll
      for (int j = 0; j < 4; j++)
        acc[i][j] = __builtin_amdgcn_mfma_f32_16x16x32_bf16(af[i], bf[j], acc[i][j], 0, 0, 0);
    __syncthreads();
    cur ^= 1;
  }
  // C/D layout: col = lane&15, row = (lane>>4)*4 + reg
#pragma unroll
  for (int i = 0; i < 4; i++)
#pragma unroll
    for (int j = 0; j < 4; j++)
#pragma unroll
      for (int r = 0; r < 4; r++) {
        int gr = m0 + wr * 64 + i * 16 + kg * 4 + r;
        int gc = n0 + wc * 64 + j * 16 + mrow;
        if (OUT == OUT_BF16) {
          ((u16*)Cv)[(size_t)blockIdx.z * sC + (size_t)gr * N + gc] = f2bf(acc[i][j][r]);
        } else {
          ((u16*)Cv)[(size_t)blockIdx.z * sC + (size_t)gr * N + gc] = f2h(acc[i][j][r]);
        }
      }
  if (SYMM && bx > by) {
    u16* Cb = (u16*)Cv + (size_t)blockIdx.z * sC;
#pragma unroll
    for (int i = 0; i < 4; i++)
#pragma unroll
      for (int j = 0; j < 4; j++) {
        int grb = m0 + wr * 64 + i * 16 + kg * 4;
        int gc = n0 + wc * 64 + j * 16 + mrow;
        ushort4v pk;
#pragma unroll
        for (int r = 0; r < 4; r++) pk[r] = f2h(acc[i][j][r]);
        *(ushort4v*)(Cb + (size_t)gc * N + grb) = pk;
      }
  }
}

// ---- Apply MFMA GEMM: 144x144 tile, 9 waves (3x3), 48x48/wave, BK=64 ----
// Grid (N9/144=8, L/144=16, G) = 512 blocks = exactly 2/CU. Uniform staging:
// 144 rows x 128B = 18432 B = 576 lanes x 16B x 2 passes -> 2 A-gloads +
// 2 B-gloads per thread per K-step. 18 MFMAs per barrier pair; 36 steps.
__global__ __launch_bounds__(576) void gemm_ap144(const u16* __restrict__ A,
                                                  const u16* __restrict__ B,
                                                  u16* __restrict__ Cv,
                                                  int N, int Kd,
                                                  size_t sA, size_t sB, size_t sC) {
  const u16* Ab = A + (size_t)blockIdx.z * sA;
  const u16* Bb = B + (size_t)blockIdx.z * sB;
  int nwg = gridDim.x * gridDim.y;
  int orig = blockIdx.y * gridDim.x + blockIdx.x;
  int wgid = xcd_swz8(orig, nwg);
  int bx = wgid % gridDim.x, by = wgid / gridDim.x;
  int m0 = by * 144, n0 = bx * 144;

  __shared__ __align__(128) char As[2][18432];
  __shared__ __align__(128) char Bs[2][18432];
  int t = threadIdx.x;                       // 0..575
  int lane = t & 63, wv = t >> 6;            // 9 waves
  int wrow = wv / 3, wcol = wv % 3;          // 3x3 wave grid
  int mrow = lane & 15, kg = lane >> 4;
  f32x4 acc[3][3];
#pragma unroll
  for (int i = 0; i < 3; i++)
#pragma unroll
    for (int j = 0; j < 3; j++) acc[i][j] = (f32x4)(0.0f);

  // staging sources: dest bytes d0 = t*16 (pass 0), d1 = 9216 + t*16 (pass 1);
  // row = byte>>7 (unchanged by swzb), col-slot = permuted bits [6:4].
  uint32_t d0 = (uint32_t)t * 16u;
  uint32_t d1 = 9216u + d0;
  uint32_t s0 = swzb(d0), s1 = swzb(d1);
  int row0 = (int)(s0 >> 7), col0 = (int)((s0 >> 4) & 7u);
  int row1 = (int)(s1 >> 7), col1 = (int)((s1 >> 4) & 7u);
  const u16* ga0 = Ab + (size_t)(m0 + row0) * Kd + col0 * 8;
  const u16* ga1 = Ab + (size_t)(m0 + row1) * Kd + col1 * 8;
  const u16* gb0 = Bb + (size_t)(n0 + row0) * Kd + col0 * 8;
  const u16* gb1 = Bb + (size_t)(n0 + row1) * Kd + col1 * 8;

  auto STAGE = [&](int buf, int k0) {
    gload16(ga0 + k0, As[buf] + wv * 1024);
    gload16(ga1 + k0, As[buf] + 9216 + wv * 1024);
    gload16(gb0 + k0, Bs[buf] + wv * 1024);
    gload16(gb1 + k0, Bs[buf] + 9216 + wv * 1024);
  };

  int nsteps = Kd >> 6;   // BK = 64
  STAGE(0, 0);
  __syncthreads();
  int cur = 0;
  for (int s = 0; s < nsteps; ++s) {
    if (s + 1 < nsteps) STAGE(cur ^ 1, (s + 1) << 6);
#pragma unroll
    for (int kk = 0; kk < 2; kk++) {
      bfrag8 af[3], bf[3];
#pragma unroll
      for (int i = 0; i < 3; i++) {
        uint32_t byte = (uint32_t)(wrow * 48 + i * 16 + mrow) * 128u +
                        (uint32_t)kk * 64u + (uint32_t)kg * 16u;
        af[i] = *(const bfrag8*)(As[cur] + swzb(byte));
      }
#pragma unroll
      for (int j = 0; j < 3; j++) {
        uint32_t byte = (uint32_t)(wcol * 48 + j * 16 + mrow) * 128u +
                        (uint32_t)kk * 64u + (uint32_t)kg * 16u;
        bf[j] = *(const bfrag8*)(Bs[cur] + swzb(byte));
      }
#pragma unroll
      for (int i = 0; i < 3; i++)
#pragma unroll
        for (int j = 0; j < 3; j++)
          acc[i][j] = __builtin_amdgcn_mfma_f32_16x16x32_bf16(af[i], bf[j], acc[i][j], 0, 0, 0);
    }
    __syncthreads();
    cur ^= 1;
  }
  // C/D layout: col = lane&15, row = (lane>>4)*4 + reg
#pragma unroll
  for (int i = 0; i < 3; i++)
#pragma unroll
    for (int j = 0; j < 3; j++)
#pragma unroll
      for (int r = 0; r < 4; r++) {
        int gr = m0 + wrow * 48 + i * 16 + kg * 4 + r;
        int gc = n0 + wcol * 48 + j * 16 + mrow;
        Cv[(size_t)blockIdx.z * sC + (size_t)gr * N + gc] = f2bf(acc[i][j][r]);
      }
}

// ---- patchsum tap: 8 contiguous fp16 at flat offset o8 + S*2305 ---------
template <int S>
__device__ __forceinline__ void tap(const u16* __restrict__ Ub, int o8, bool tok,
                                    const bool* md, int b, float* acc) {
  constexpr int REM = ((S % 8) + 8) % 8;
  int off = tok ? (o8 + S * 2305) : (8 + REM);
  float v[8];
  if constexpr (REM == 0) {
    ushort8 w = *(const ushort8*)(Ub + off);
#pragma unroll
    for (int i = 0; i < 8; i++) v[i] = h2f(w[i]);
  } else if constexpr (REM == 1) {
    ushort8 w = *(const ushort8*)(Ub + off - 1);
    u16 sc = Ub[off + 7];
#pragma unroll
    for (int i = 0; i < 7; i++) v[i] = h2f(w[i + 1]);
    v[7] = h2f(sc);
  } else {  // REM == 7
    u16 sc = Ub[off];
    ushort8 w = *(const ushort8*)(Ub + off + 1);
    v[0] = h2f(sc);
#pragma unroll
    for (int i = 1; i < 8; i++) v[i] = h2f(w[i - 1]);
  }
#pragma unroll
  for (int i = 0; i < 8; i++) acc[i] += (tok && md[b + i]) ? v[i] : 0.f;
}

// ---- 9-tap diagonal patch-sum * 1/norm (U fp16 in, V fp16 out) ----------
__global__ __launch_bounds__(256) void k_patchsum(const u16* __restrict__ U,
                                                  u16* __restrict__ V,
                                                  const float* __restrict__ ninv,
                                                  int b0) {
  int blk = xcd_swz8(blockIdx.x, gridDim.x);
  int bz = blockIdx.z;
  int o8 = (blk * 256 + (int)threadIdx.x) * 8;
  int R = o8 / L_;
  int col = o8 - R * L_;
  const u16* Ub = U + (size_t)bz * L_ * L_;
  u16* Vb = V + (size_t)bz * L_ * L_;
  int hq = R / h_, wq = R % h_, ps = col / h_, qs0 = col % h_;
  bool ra[3], rb[3], ca[3];
#pragma unroll
  for (int a = 0; a < 3; a++) {
    ra[a] = (unsigned)(hq - 1 + a) < (unsigned)h_;
    rb[a] = (unsigned)(wq - 1 + a) < (unsigned)h_;
    ca[a] = (unsigned)(ps - 1 + a) < (unsigned)h_;
  }
  bool md[10];
#pragma unroll
  for (int d = 0; d < 10; d++) md[d] = (unsigned)(qs0 - 1 + d) < (unsigned)h_;

  float acc[8];
#pragma unroll
  for (int i = 0; i < 8; i++) acc[i] = 0.f;

  bool t0 = ra[0] && ca[0];
  bool t1 = ra[1] && ca[1];
  bool t2 = ra[2] && ca[2];
  tap<-49>(Ub, o8, t0 && rb[0], md, 0, acc);
  tap<-48>(Ub, o8, t0 && rb[1], md, 1, acc);
  tap<-47>(Ub, o8, t0 && rb[2], md, 2, acc);
  tap<-1>(Ub, o8, t1 && rb[0], md, 0, acc);
  tap<0>(Ub, o8, t1 && rb[1], md, 1, acc);
  tap<1>(Ub, o8, t1 && rb[2], md, 2, acc);
  tap<47>(Ub, o8, t2 && rb[0], md, 0, acc);
  tap<48>(Ub, o8, t2 && rb[1], md, 1, acc);
  tap<49>(Ub, o8, t2 && rb[2], md, 2, acc);

  const float* nvb = ninv + (size_t)(b0 + bz) * L_ + col;
  ushort8 ov;
#pragma unroll
  for (int i = 0; i < 8; i++) ov[i] = f2h(acc[i] * nvb[i]);
  *(ushort8*)(Vb + o8) = ov;
}

// ---- fused fuse1 + fuse2 + masked softmax -> bf16 attention -------------
__global__ __launch_bounds__(256) void k_fsm(const u16* __restrict__ V1,
                                             const float* __restrict__ mm,
                                             u16* __restrict__ Aout,
                                             int b0) {
  int i = xcd_swz8(blockIdx.x, L_), bz = blockIdx.y;
  int hq = i / h_, wq = i % h_;
  const u16* Vb = V1 + (size_t)bz * L_ * L_;
  const float* mmb = mm + (size_t)(b0 + bz) * L_;
  u16* arow = Aout + ((size_t)bz * L_ + i) * L_;
  int t = threadIdx.x;

  uint32_t rowBase[3];
  bool rw0[3], rw1[3], rw2[3];
#pragma unroll
  for (int d2 = 0; d2 < 3; d2++) {
    int TA = wq * h_ + hq + (d2 - 1);
    bool ok = (TA >= 0) && (TA < L_);
    int TAc = ok ? TA : 0;
    int iB = (TAc % h_) * h_ + TAc / h_;
    rowBase[d2] = (uint32_t)(iB * L_);
    rw0[d2] = ok && (iB - 1 >= 0);
    rw1[d2] = ok;
    rw2[d2] = ok && (iB + 1 < L_);
  }
  bool fastR = rw0[0] && rw1[0] && rw2[0] && rw0[1] && rw1[1] && rw2[1] &&
               rw0[2] && rw1[2] && rw2[2];

  float y[9];
  float mx = -3.0e38f;

  auto full_col = [&](int j, int jy) -> float {
    int jB0 = (jy >= 1) ? (j - h_) : (j + (L_ - h_ - 1));
    int jB1 = j;
    int jB2 = (jy <= h_ - 2) ? (j + h_) : (j - (L_ - h_ - 1));
    bool tb0 = (j > 0), tb2 = (j < L_ - 1);
    float s = 0.f;
    {
      uint32_t oc = rowBase[0] + (uint32_t)jB0;
      bool w0 = rw0[0] && tb0 && (jB0 > 0);
      bool w1 = rw1[0] && tb0;
      bool w2 = rw2[0] && tb0 && (jB0 < L_ - 1);
      float vm = h2f(Vb[w0 ? oc - (L_ + 1) : 0u]);
      float vc = h2f(Vb[w1 ? oc : 0u]);
      float vp = h2f(Vb[w2 ? oc + (L_ + 1) : 0u]);
      s += (w0 ? vm : 0.f) + (w1 ? vc : 0.f) + (w2 ? vp : 0.f);
    }
    {
      uint32_t oc = rowBase[1] + (uint32_t)jB1;
      bool w0 = rw0[1] && (jB1 > 0);
      bool w1 = rw1[1];
      bool w2 = rw2[1] && (jB1 < L_ - 1);
      float vm = h2f(Vb[w0 ? oc - (L_ + 1) : 0u]);
      float vc = h2f(Vb[w1 ? oc : 0u]);
      float vp = h2f(Vb[w2 ? oc + (L_ + 1) : 0u]);
      s += (w0 ? vm : 0.f) + (w1 ? vc : 0.f) + (w2 ? vp : 0.f);
    }
    {
      uint32_t oc = rowBase[2] + (uint32_t)jB2;
      bool w0 = rw0[2] && tb2 && (jB2 > 0);
      bool w1 = rw1[2] && tb2;
      bool w2 = rw2[2] && tb2 && (jB2 < L_ - 1);
      float vm = h2f(Vb[w0 ? oc - (L_ + 1) : 0u]);
      float vc = h2f(Vb[w1 ? oc : 0u]);
      float vp = h2f(Vb[w2 ? oc + (L_ + 1) : 0u]);
      s += (w0 ? vm : 0.f) + (w1 ? vc : 0.f) + (w2 ? vp : 0.f);
    }
    return s;
  };

  {
    int j = t;
    float zv = full_col(j, t / h_) * mmb[j] * SCALE_;
    y[0] = zv;
    mx = fmaxf(mx, zv);
  }
  if (fastR) {
#pragma unroll
    for (int cc = 1; cc <= 7; cc++) {
      int j = cc * 256 + t;
      float s = 0.f;
#pragma unroll
      for (int d2 = 0; d2 < 3; d2++) {
        uint32_t oc = rowBase[d2] + (uint32_t)(j + h_ * (d2 - 1));
        s += h2f(Vb[oc - (L_ + 1)]) + h2f(Vb[oc]) + h2f(Vb[oc + (L_ + 1)]);
      }
      float zv = s * mmb[j] * SCALE_;
      y[cc] = zv;
      mx = fmaxf(mx, zv);
    }
  } else {
#pragma unroll
    for (int cc = 1; cc <= 7; cc++) {
      int j = cc * 256 + t;
      float s = 0.f;
#pragma unroll
      for (int d2 = 0; d2 < 3; d2++) {
        uint32_t oc = rowBase[d2] + (uint32_t)(j + h_ * (d2 - 1));
        float vm = h2f(Vb[rw0[d2] ? oc - (L_ + 1) : 0u]);
        float vc = h2f(Vb[rw1[d2] ? oc : 0u]);
        float vp = h2f(Vb[rw2[d2] ? oc + (L_ + 1) : 0u]);
        s += (rw0[d2] ? vm : 0.f) + (rw1[d2] ? vc : 0.f) + (rw2[d2] ? vp : 0.f);
      }
      float zv = s * mmb[j] * SCALE_;
      y[cc] = zv;
      mx = fmaxf(mx, zv);
    }
  }
  {
    int j = 2048 + t;
    float zv = full_col(j, j / h_) * mmb[j] * SCALE_;
    y[8] = zv;
    mx = fmaxf(mx, zv);
  }

  int lane = t & 63, wid = t >> 6;
  __shared__ float wredm[4];
  __shared__ float wreds[4];
#pragma unroll
  for (int o = 32; o >= 1; o >>= 1) mx = fmaxf(mx, __shfl_xor(mx, o, 64));
  if (lane == 0) wredm[wid] = mx;
  __syncthreads();
  float MX = fmaxf(fmaxf(wredm[0], wredm[1]), fmaxf(wredm[2], wredm[3]));
  float sm = 0.f;
#pragma unroll
  for (int cc = 0; cc < 9; cc++) {
    y[cc] = __expf(y[cc] - MX);
    sm += y[cc];
  }
#pragma unroll
  for (int o = 32; o >= 1; o >>= 1) sm += __shfl_xor(sm, o, 64);
  if (lane == 0) wreds[wid] = sm;
  __syncthreads();
  float inv = 1.0f / (wreds[0] + wreds[1] + wreds[2] + wreds[3]);
#pragma unroll
  for (int cc = 0; cc < 9; cc++) {
    int j = cc * 256 + t;
    arow[j] = f2bf(y[cc] * inv * mmb[j]);
  }
}

// ---- deconv parity-gather scatter (P bf16, 4 channels/thread) -----------
__global__ __launch_bounds__(256) void k_scatter(const u16* __restrict__ P,
                                                 float* __restrict__ out) {
  int idx = blockIdx.x * 256 + threadIdx.x;   // over B*H*W*32
  int c4 = idx & 31;
  int r = idx >> 5;
  int xx = r % W_; r /= W_;
  int y = r % H_;
  int bz = r / H_;
  const u16* Pb = P + (size_t)bz * L_ * N9_;
  int yo[2], ya[2], ny = 0;
  if (y & 1) { yo[0] = y >> 1; ya[0] = 1; ny = 1; }
  else {
    yo[0] = y >> 1; ya[0] = 0; ny = 1;
    if (y >= 2) { yo[1] = (y >> 1) - 1; ya[1] = 2; ny = 2; }
  }
  int xo[2], xa[2], nx = 0;
  if (xx & 1) { xo[0] = xx >> 1; xa[0] = 1; nx = 1; }
  else {
    xo[0] = xx >> 1; xa[0] = 0; nx = 1;
    if (xx >= 2) { xo[1] = (xx >> 1) - 1; xa[1] = 2; nx = 2; }
  }
  float s[4] = {0.f, 0.f, 0.f, 0.f};
  for (int i = 0; i < ny; i++)
    for (int j = 0; j < nx; j++) {
      size_t off = (size_t)(yo[i] * h_ + xo[j]) * N9_ + (ya[i] * 3 + xa[j]) * C_ + 4 * c4;
      ushort4v w = *(const ushort4v*)(Pb + off);
#pragma unroll
      for (int k = 0; k < 4; k++) s[k] += bf2f(w[k]);
    }
  f32x4 o;
#pragma unroll
  for (int k = 0; k < 4; k++) o[k] = 0.25f * s[k];
  *(f32x4*)(out + ((size_t)bz * H_ + y) * (size_t)W_ * C_ + (size_t)xx * C_ + 4 * c4) = o;
}

}  // namespace

extern "C" void kernel_launch(void* const* d_in, const int* in_sizes, int n_in,
                              void* d_out, int out_size, void* d_ws, size_t ws_size,
                              hipStream_t stream) {
  (void)in_sizes; (void)n_in; (void)out_size;
  const float* x = (const float*)d_in[0];
  const float* mask = (const float*)d_in[1];
  float* out = (float*)d_out;
  char* ws = (char*)d_ws;

  const size_t szF3 = (size_t)B_ * L_ * K3_ * sizeof(u16);
  const size_t szSm = (size_t)B_ * L_ * sizeof(float);
  const size_t off_F3a = 0;
  const size_t off_F3b = off_F3a + szF3;
  const size_t off_S = off_F3b + szF3;
  const size_t off_md = off_S + szSm;
  const size_t off_mm = off_md + szSm;
  const size_t off_nv = off_mm + szSm;
  const size_t off_fixed_end = off_nv + szSm;

  const size_t perXp = (size_t)N9_ * L_ * sizeof(u16);   // 5.3 MB
  const size_t perU = (size_t)L_ * L_ * sizeof(u16);     // 10.6 MB (fp16)
  const size_t perV = (size_t)L_ * L_ * sizeof(u16);     // 10.6 MB (fp16)
  int G = 4;
  while (G > 1 && off_fixed_end + (size_t)G * (perXp + perU + perV) > ws_size) G >>= 1;

  const size_t off_XpT = off_fixed_end;
  const size_t off_U = off_XpT + (size_t)G * perXp;
  const size_t off_V = off_U + (size_t)G * perU;

  u16* F3a = (u16*)(ws + off_F3a);
  u16* F3b = (u16*)(ws + off_F3b);
  float* S = (float*)(ws + off_S);
  float* md = (float*)(ws + off_md);
  float* mm = (float*)(ws + off_mm);
  float* nv = (float*)(ws + off_nv);
  u16* XpT = (u16*)(ws + off_XpT);
  u16* U = (u16*)(ws + off_U);
  u16* V = (u16*)(ws + off_V);
  u16* Abuf = (u16*)(ws + off_U);   // alias U (U dead after patchsum)
  u16* Pbuf = (u16*)(ws + off_V);   // alias V (V dead after fsm)

  k_down<<<dim3(B_ * L_), dim3(C_), 0, stream>>>(x, F3a, F3b, S);
  k_mask<<<dim3((B_ * L_) / 256), dim3(256), 0, stream>>>(mask, md);
  k_mmnorm<<<dim3((B_ * L_) / 256), dim3(256), 0, stream>>>(S, md, mm, nv);

  for (int sb = 0; sb < B_; sb += G) {
    const float* xs = x + (size_t)sb * H_ * W_ * C_;
    k_xpack<<<dim3(L_ / 32, N9_ / 64, G), dim3(256), 0, stream>>>(xs, XpT);
    // Gram (symmetric): 171 upper-triangle tiles of the 18x18 grid
    gemm_bt<OUT_F16, true><<<dim3(171, 1, G), dim3(256), 0, stream>>>(
        F3a + (size_t)sb * L_ * K3_, F3b + (size_t)sb * L_ * K3_, (void*)U,
        L_, K3_, (size_t)L_ * K3_, (size_t)L_ * K3_, (size_t)L_ * L_);
    k_patchsum<<<dim3((L_ * L_) / (256 * 8), 1, G), dim3(256), 0, stream>>>(U, V, nv, sb);
    k_fsm<<<dim3(L_, G), dim3(256), 0, stream>>>(V, mm, Abuf, sb);
    // Apply: 144x144 tiles, BK=64 -> (8, 16, 4) = 512 blocks = exactly 2/CU
    gemm_ap144<<<dim3(N9_ / 144, L_ / 144, G), dim3(576), 0, stream>>>(
        Abuf, XpT, Pbuf, N9_, L_,
        (size_t)L_ * L_, (size_t)N9_ * L_, (size_t)L_ * N9_);
    k_scatter<<<dim3((G * H_ * W_ * C_ / 4) / 256), dim3(256), 0, stream>>>(
        Pbuf, out + (size_t)sb * H_ * W_ * C_);
  }
}

// Round 16
// 185.086 us; speedup vs baseline: 1.0353x; 1.0353x over previous
//
#include <hip/hip_runtime.h>
#include <hip/hip_fp16.h>
#include <stdint.h>
#include <string.h>

// ContextualAttention on MI355X.  (R14 configuration — best verified state.)
// Pipeline:
//  k_down:    x -> (bf16x3 packed F3a/F3b for Gram GEMM) + per-pixel sumsq S
//  k_mask:    mask -> 2x2 avg-pooled md
//  k_mmnorm:  md,S -> mm (valid-patch mask), ninv (1/patch-norm)
//  k_xpack:   x -> XpT[j=(a,b,c)][l=(p,q)] bf16 (deconv weights, transposed for GEMM B)
//  gemm_bt<F16,SYMM>: U(fp16) = F3a . F3b^T  (Gram; 171 upper-triangle 128^2 tiles)
//  k_patchsum:V(fp16)[hw][pq] = 9-tap diag stencil of U * ninv[pq]
//  k_fsm:     fused fuse1 + fuse2 + masked softmax -> A (bf16)
//  gemm_ap144: P(bf16) = A . XpT^T   [144x144 tiles, 9 waves, BK=32, 512 blocks
//              = 2/CU exact; UNIFORM staging: 1 A- + 1 B-gload per thread/K-step]
//  k_scatter: out = parity-gather of P / 4  (4 channels/thread)

namespace {

constexpr int B_ = 4;
constexpr int H_ = 96;
constexpr int W_ = 96;
constexpr int C_ = 128;
constexpr int h_ = 48;
constexpr int L_ = 2304;   // h_*h_
constexpr int N9_ = 1152;  // 9*C_
constexpr int K3_ = 384;   // 3*C_  bf16x3 packed K
constexpr float SCALE_ = 10.0f;
constexpr float EPS_ = 1e-4f;

constexpr int OUT_F16 = 1;
constexpr int OUT_BF16 = 2;

typedef unsigned short u16;
typedef __attribute__((ext_vector_type(8))) short bfrag8;            // 8 bf16
typedef __attribute__((ext_vector_type(8))) unsigned short ushort8;  // 16B
typedef __attribute__((ext_vector_type(4))) unsigned short ushort4v; // 8B
typedef __attribute__((ext_vector_type(4))) float f32x4;
typedef __attribute__((ext_vector_type(2))) float f32x2;

__device__ __forceinline__ u16 f2bf(float f) {
  uint32_t x;
  __builtin_memcpy(&x, &f, 4);
  uint32_t lsb = (x >> 16) & 1u;
  x += 0x7fffu + lsb;
  return (u16)(x >> 16);
}
__device__ __forceinline__ float bf2f(u16 u) {
  uint32_t v = ((uint32_t)u) << 16;
  float f;
  __builtin_memcpy(&f, &v, 4);
  return f;
}
__device__ __forceinline__ u16 f2h(float f) {
  __half h = __float2half(f);
  u16 u;
  __builtin_memcpy(&u, &h, 2);
  return u;
}
__device__ __forceinline__ float h2f(u16 u) {
  __half h;
  __builtin_memcpy(&h, &u, 2);
  return __half2float(h);
}

// async global(16B/lane) -> LDS (wave-uniform base + lane*16)
__device__ __forceinline__ void gload16(const u16* g, void* l) {
  __builtin_amdgcn_global_load_lds(
      (const __attribute__((address_space(1))) void*)g,
      (__attribute__((address_space(3))) void*)l, 16, 0, 0);
}

// XCD-chunked bijective block swizzle (m204 variant, any nwg)
__device__ __forceinline__ int xcd_swz8(int orig, int nwg) {
  int q = nwg >> 3, r = nwg & 7;
  int xcd = orig & 7, pos = orig >> 3;
  return (xcd < r ? xcd * (q + 1) : r * (q + 1) + (xcd - r) * q) + pos;
}

// LDS byte-offset swizzle (involution): XOR bits[9:7] onto 16B-slot bits[6:4].
__device__ __forceinline__ uint32_t swzb(uint32_t byte) {
  return byte ^ (((byte >> 7) & 7u) << 4);
}

// ---- downscale (2x2 avg) + bf16x3 pack + per-pixel sum of squares -------
__global__ __launch_bounds__(128) void k_down(const float* __restrict__ x,
                                              u16* __restrict__ F3a,
                                              u16* __restrict__ F3b,
                                              float* __restrict__ S) {
  int blk = blockIdx.x;
  int b = blk / L_, l = blk % L_;
  int p = l / h_, q = l % h_;
  int c = threadIdx.x;
  const float* xb = x + (((size_t)b * H_ + 2 * p) * W_ + 2 * q) * C_ + c;
  float v = 0.25f * (xb[0] + xb[C_] + xb[(size_t)W_ * C_] + xb[(size_t)W_ * C_ + C_]);
  u16 hi = f2bf(v);
  u16 lo = f2bf(v - bf2f(hi));
  size_t base = ((size_t)b * L_ + l) * K3_;
  F3a[base + c] = hi; F3a[base + 128 + c] = hi; F3a[base + 256 + c] = lo;
  F3b[base + c] = hi; F3b[base + 128 + c] = lo; F3b[base + 256 + c] = hi;
  float ss = v * v;
#pragma unroll
  for (int o = 32; o >= 1; o >>= 1) ss += __shfl_xor(ss, o, 64);
  __shared__ float w2[2];
  if ((c & 63) == 0) w2[c >> 6] = ss;
  __syncthreads();
  if (c == 0) S[(size_t)b * L_ + l] = w2[0] + w2[1];
}

// ---- mask 2x2 avg-pool --------------------------------------------------
__global__ __launch_bounds__(256) void k_mask(const float* __restrict__ mask,
                                              float* __restrict__ md) {
  int i = blockIdx.x * 256 + threadIdx.x;
  int b = i / L_, l = i % L_, p = l / h_, q = l % h_;
  const float* mb = mask + ((size_t)b * H_ + 2 * p) * W_ + 2 * q;
  md[i] = 0.25f * (mb[0] + mb[1] + mb[W_] + mb[W_ + 1]);
}

// ---- valid-patch mask + 1/patch-norm ------------------------------------
__global__ __launch_bounds__(256) void k_mmnorm(const float* __restrict__ S,
                                                const float* __restrict__ md,
                                                float* __restrict__ mm,
                                                float* __restrict__ ninv) {
  int i = blockIdx.x * 256 + threadIdx.x;
  int b = i / L_, l = i % L_, p = l / h_, q = l % h_;
  float ssum = 0.f, msum = 0.f;
#pragma unroll
  for (int a = 0; a < 3; a++) {
    int rp = p - 1 + a;
#pragma unroll
    for (int bb = 0; bb < 3; bb++) {
      int rq = q - 1 + bb;
      bool ok = ((unsigned)rp < (unsigned)h_) && ((unsigned)rq < (unsigned)h_);
      int idx = ok ? (b * L_ + rp * h_ + rq) : 0;
      float sv = S[idx], mv = md[idx];
      if (ok) { ssum += sv; msum += mv; }
    }
  }
  mm[i] = (msum == 0.f) ? 1.f : 0.f;
  float n = fmaxf(sqrtf(ssum), EPS_);
  ninv[i] = 1.f / n;
}

// ---- pack deconv weights transposed: XpT[bz][j=(a,bb,c)][l=(p,q)] -------
__global__ __launch_bounds__(256) void k_xpack(const float* __restrict__ x,
                                               u16* __restrict__ XpT) {
  int lt = blockIdx.x * 32, jt = blockIdx.y * 64, bz = blockIdx.z;
  __shared__ u16 tile[32][65];
  int t = threadIdx.x;
  int jj = t & 63, lq = t >> 6;
  for (int pass = 0; pass < 8; ++pass) {
    int ll = pass * 4 + lq;
    int l = lt + ll;
    int p = l / h_, q = l % h_;
    int j = jt + jj;
    int a = j / 384, rem = j % 384, bb = rem / 128, c = rem % 128;
    int gy = 2 * p + a, gx = 2 * q + bb;
    float v = 0.f;
    if (gy < H_ && gx < W_) v = x[(((size_t)bz * H_ + gy) * W_ + gx) * C_ + c];
    tile[ll][jj] = f2bf(v);
  }
  __syncthreads();
  int lw = t & 31, jq = t >> 5;
  for (int pass = 0; pass < 8; ++pass) {
    int j2 = pass * 8 + jq;
    XpT[((size_t)bz * N9_ + jt + j2) * L_ + lt + lw] = tile[lw][j2];
  }
}

// ---- Gram MFMA GEMM (R7-proven 128^2 structure, SYMM triangle) ----------
template <int OUT, bool SYMM>
__global__ __launch_bounds__(256) void gemm_bt(const u16* __restrict__ A,
                                               const u16* __restrict__ B,
                                               void* __restrict__ Cv,
                                               int N, int Kd,
                                               size_t sA, size_t sB, size_t sC) {
  const u16* Ab = A + (size_t)blockIdx.z * sA;
  const u16* Bb = B + (size_t)blockIdx.z * sB;
  int bx, by;
  if (SYMM) {
    int wgid = xcd_swz8(blockIdx.x, gridDim.x);   // 171 tiles
    int t2 = wgid, row = 0, len = 18;
    while (t2 >= len) { t2 -= len; --len; ++row; }
    by = row;
    bx = row + t2;
  } else {
    int nwg = gridDim.x * gridDim.y;
    int orig = blockIdx.y * gridDim.x + blockIdx.x;
    int wgid = xcd_swz8(orig, nwg);
    bx = wgid % gridDim.x;
    by = wgid / gridDim.x;
  }
  int m0 = by * 128, n0 = bx * 128;

  __shared__ __align__(128) char As[2][8192];
  __shared__ __align__(128) char Bs[2][8192];
  int t = threadIdx.x;
  int lane = t & 63, wv = t >> 6, wr = wv >> 1, wc = wv & 1;
  int mrow = lane & 15, kg = lane >> 4;
  f32x4 acc[4][4];
#pragma unroll
  for (int i = 0; i < 4; i++)
#pragma unroll
    for (int j = 0; j < 4; j++) acc[i][j] = (f32x4)(0.0f);

  uint32_t d16 = (uint32_t)t * 16u;
  uint32_t sz = swzb(d16);
  int rowp = (int)(sz >> 6);        // 0..63 permuted row (64B rows)
  int kcp = (int)((sz >> 4) & 3u);  // permuted 16B chunk in row
  const u16* ga0 = Ab + (size_t)(m0 + rowp) * Kd + kcp * 8;
  const u16* ga1 = Ab + (size_t)(m0 + 64 + rowp) * Kd + kcp * 8;
  const u16* gb0 = Bb + (size_t)(n0 + rowp) * Kd + kcp * 8;
  const u16* gb1 = Bb + (size_t)(n0 + 64 + rowp) * Kd + kcp * 8;

  auto STAGE = [&](int buf, int k0) {
    gload16(ga0 + k0, As[buf] + wv * 1024);
    gload16(ga1 + k0, As[buf] + 4096 + wv * 1024);
    gload16(gb0 + k0, Bs[buf] + wv * 1024);
    gload16(gb1 + k0, Bs[buf] + 4096 + wv * 1024);
  };

  int nsteps = Kd >> 5;
  STAGE(0, 0);
  __syncthreads();
  int cur = 0;
  for (int s = 0; s < nsteps; ++s) {
    if (s + 1 < nsteps) STAGE(cur ^ 1, (s + 1) << 5);
    bfrag8 af[4], bf[4];
#pragma unroll
    for (int i = 0; i < 4; i++) {
      uint32_t byte = (uint32_t)(wr * 64 + i * 16 + mrow) * 64u + (uint32_t)kg * 16u;
      af[i] = *(const bfrag8*)(As[cur] + swzb(byte));
    }
#pragma unroll
    for (int i = 0; i < 4; i++) {
      uint32_t byte = (uint32_t)(wc * 64 + i * 16 + mrow) * 64u + (uint32_t)kg * 16u;
      bf[i] = *(const bfrag8*)(Bs[cur] + swzb(byte));
    }
#pragma unroll
    for (int i = 0; i < 4; i++)
#pragma unroll
      for (int j = 0; j < 4; j++)
        acc[i][j] = __builtin_amdgcn_mfma_f32_16x16x32_bf16(af[i], bf[j], acc[i][j], 0, 0, 0);
    __syncthreads();
    cur ^= 1;
  }
  // C/D layout: col = lane&15, row = (lane>>4)*4 + reg
#pragma unroll
  for (int i = 0; i < 4; i++)
#pragma unroll
    for (int j = 0; j < 4; j++)
#pragma unroll
      for (int r = 0; r < 4; r++) {
        int gr = m0 + wr * 64 + i * 16 + kg * 4 + r;
        int gc = n0 + wc * 64 + j * 16 + mrow;
        if (OUT == OUT_BF16) {
          ((u16*)Cv)[(size_t)blockIdx.z * sC + (size_t)gr * N + gc] = f2bf(acc[i][j][r]);
        } else {
          ((u16*)Cv)[(size_t)blockIdx.z * sC + (size_t)gr * N + gc] = f2h(acc[i][j][r]);
        }
      }
  if (SYMM && bx > by) {
    u16* Cb = (u16*)Cv + (size_t)blockIdx.z * sC;
#pragma unroll
    for (int i = 0; i < 4; i++)
#pragma unroll
      for (int j = 0; j < 4; j++) {
        int grb = m0 + wr * 64 + i * 16 + kg * 4;
        int gc = n0 + wc * 64 + j * 16 + mrow;
        ushort4v pk;
#pragma unroll
        for (int r = 0; r < 4; r++) pk[r] = f2h(acc[i][j][r]);
        *(ushort4v*)(Cb + (size_t)gc * N + grb) = pk;
      }
  }
}

// ---- Apply MFMA GEMM: 144x144 tile, 9 waves (3x3), 48x48/wave, BK=32 ----
// Grid (N9/144=8, L/144=16, G) = 512 blocks = exactly 2/CU. Uniform staging:
// 144 rows x 64B = 9216 B = 576 lanes x 16B -> 1 A-gload + 1 B-gload per
// thread per K-step. Proven 2-phase sync structure (R14: 61.4 us, race-free).
__global__ __launch_bounds__(576) void gemm_ap144(const u16* __restrict__ A,
                                                  const u16* __restrict__ B,
                                                  u16* __restrict__ Cv,
                                                  int N, int Kd,
                                                  size_t sA, size_t sB, size_t sC) {
  const u16* Ab = A + (size_t)blockIdx.z * sA;
  const u16* Bb = B + (size_t)blockIdx.z * sB;
  int nwg = gridDim.x * gridDim.y;
  int orig = blockIdx.y * gridDim.x + blockIdx.x;
  int wgid = xcd_swz8(orig, nwg);
  int bx = wgid % gridDim.x, by = wgid / gridDim.x;
  int m0 = by * 144, n0 = bx * 144;

  __shared__ __align__(128) char As[2][9216];
  __shared__ __align__(128) char Bs[2][9216];
  int t = threadIdx.x;                       // 0..575
  int lane = t & 63, wv = t >> 6;            // 9 waves
  int wrow = wv / 3, wcol = wv % 3;          // 3x3 wave grid
  int mrow = lane & 15, kg = lane >> 4;
  f32x4 acc[3][3];
#pragma unroll
  for (int i = 0; i < 3; i++)
#pragma unroll
    for (int j = 0; j < 3; j++) acc[i][j] = (f32x4)(0.0f);

  uint32_t d16 = (uint32_t)t * 16u;          // 0..9200
  uint32_t sz = swzb(d16);
  int rowp = (int)(sz >> 6);                 // 0..143 permuted row
  int kcp = (int)((sz >> 4) & 3u);
  const u16* ga = Ab + (size_t)(m0 + rowp) * Kd + kcp * 8;
  const u16* gb = Bb + (size_t)(n0 + rowp) * Kd + kcp * 8;

  auto STAGE = [&](int buf, int k0) {
    gload16(ga + k0, As[buf] + wv * 1024);
    gload16(gb + k0, Bs[buf] + wv * 1024);
  };

  int nsteps = Kd >> 5;
  STAGE(0, 0);
  __syncthreads();
  int cur = 0;
  for (int s = 0; s < nsteps; ++s) {
    if (s + 1 < nsteps) STAGE(cur ^ 1, (s + 1) << 5);
    bfrag8 af[3], bf[3];
#pragma unroll
    for (int i = 0; i < 3; i++) {
      uint32_t byte = (uint32_t)(wrow * 48 + i * 16 + mrow) * 64u + (uint32_t)kg * 16u;
      af[i] = *(const bfrag8*)(As[cur] + swzb(byte));
    }
#pragma unroll
    for (int j = 0; j < 3; j++) {
      uint32_t byte = (uint32_t)(wcol * 48 + j * 16 + mrow) * 64u + (uint32_t)kg * 16u;
      bf[j] = *(const bfrag8*)(Bs[cur] + swzb(byte));
    }
#pragma unroll
    for (int i = 0; i < 3; i++)
#pragma unroll
      for (int j = 0; j < 3; j++)
        acc[i][j] = __builtin_amdgcn_mfma_f32_16x16x32_bf16(af[i], bf[j], acc[i][j], 0, 0, 0);
    __syncthreads();
    cur ^= 1;
  }
  // C/D layout: col = lane&15, row = (lane>>4)*4 + reg
#pragma unroll
  for (int i = 0; i < 3; i++)
#pragma unroll
    for (int j = 0; j < 3; j++)
#pragma unroll
      for (int r = 0; r < 4; r++) {
        int gr = m0 + wrow * 48 + i * 16 + kg * 4 + r;
        int gc = n0 + wcol * 48 + j * 16 + mrow;
        Cv[(size_t)blockIdx.z * sC + (size_t)gr * N + gc] = f2bf(acc[i][j][r]);
      }
}

// ---- patchsum tap: 8 contiguous fp16 at flat offset o8 + S*2305 ---------
template <int S>
__device__ __forceinline__ void tap(const u16* __restrict__ Ub, int o8, bool tok,
                                    const bool* md, int b, float* acc) {
  constexpr int REM = ((S % 8) + 8) % 8;
  int off = tok ? (o8 + S * 2305) : (8 + REM);
  float v[8];
  if constexpr (REM == 0) {
    ushort8 w = *(const ushort8*)(Ub + off);
#pragma unroll
    for (int i = 0; i < 8; i++) v[i] = h2f(w[i]);
  } else if constexpr (REM == 1) {
    ushort8 w = *(const ushort8*)(Ub + off - 1);
    u16 sc = Ub[off + 7];
#pragma unroll
    for (int i = 0; i < 7; i++) v[i] = h2f(w[i + 1]);
    v[7] = h2f(sc);
  } else {  // REM == 7
    u16 sc = Ub[off];
    ushort8 w = *(const ushort8*)(Ub + off + 1);
    v[0] = h2f(sc);
#pragma unroll
    for (int i = 1; i < 8; i++) v[i] = h2f(w[i - 1]);
  }
#pragma unroll
  for (int i = 0; i < 8; i++) acc[i] += (tok && md[b + i]) ? v[i] : 0.f;
}

// ---- 9-tap diagonal patch-sum * 1/norm (U fp16 in, V fp16 out) ----------
__global__ __launch_bounds__(256) void k_patchsum(const u16* __restrict__ U,
                                                  u16* __restrict__ V,
                                                  const float* __restrict__ ninv,
                                                  int b0) {
  int blk = xcd_swz8(blockIdx.x, gridDim.x);
  int bz = blockIdx.z;
  int o8 = (blk * 256 + (int)threadIdx.x) * 8;
  int R = o8 / L_;
  int col = o8 - R * L_;
  const u16* Ub = U + (size_t)bz * L_ * L_;
  u16* Vb = V + (size_t)bz * L_ * L_;
  int hq = R / h_, wq = R % h_, ps = col / h_, qs0 = col % h_;
  bool ra[3], rb[3], ca[3];
#pragma unroll
  for (int a = 0; a < 3; a++) {
    ra[a] = (unsigned)(hq - 1 + a) < (unsigned)h_;
    rb[a] = (unsigned)(wq - 1 + a) < (unsigned)h_;
    ca[a] = (unsigned)(ps - 1 + a) < (unsigned)h_;
  }
  bool md[10];
#pragma unroll
  for (int d = 0; d < 10; d++) md[d] = (unsigned)(qs0 - 1 + d) < (unsigned)h_;

  float acc[8];
#pragma unroll
  for (int i = 0; i < 8; i++) acc[i] = 0.f;

  bool t0 = ra[0] && ca[0];
  bool t1 = ra[1] && ca[1];
  bool t2 = ra[2] && ca[2];
  tap<-49>(Ub, o8, t0 && rb[0], md, 0, acc);
  tap<-48>(Ub, o8, t0 && rb[1], md, 1, acc);
  tap<-47>(Ub, o8, t0 && rb[2], md, 2, acc);
  tap<-1>(Ub, o8, t1 && rb[0], md, 0, acc);
  tap<0>(Ub, o8, t1 && rb[1], md, 1, acc);
  tap<1>(Ub, o8, t1 && rb[2], md, 2, acc);
  tap<47>(Ub, o8, t2 && rb[0], md, 0, acc);
  tap<48>(Ub, o8, t2 && rb[1], md, 1, acc);
  tap<49>(Ub, o8, t2 && rb[2], md, 2, acc);

  const float* nvb = ninv + (size_t)(b0 + bz) * L_ + col;
  ushort8 ov;
#pragma unroll
  for (int i = 0; i < 8; i++) ov[i] = f2h(acc[i] * nvb[i]);
  *(ushort8*)(Vb + o8) = ov;
}

// ---- fused fuse1 + fuse2 + masked softmax -> bf16 attention -------------
__global__ __launch_bounds__(256) void k_fsm(const u16* __restrict__ V1,
                                             const float* __restrict__ mm,
                                             u16* __restrict__ Aout,
                                             int b0) {
  int i = xcd_swz8(blockIdx.x, L_), bz = blockIdx.y;
  int hq = i / h_, wq = i % h_;
  const u16* Vb = V1 + (size_t)bz * L_ * L_;
  const float* mmb = mm + (size_t)(b0 + bz) * L_;
  u16* arow = Aout + ((size_t)bz * L_ + i) * L_;
  int t = threadIdx.x;

  uint32_t rowBase[3];
  bool rw0[3], rw1[3], rw2[3];
#pragma unroll
  for (int d2 = 0; d2 < 3; d2++) {
    int TA = wq * h_ + hq + (d2 - 1);
    bool ok = (TA >= 0) && (TA < L_);
    int TAc = ok ? TA : 0;
    int iB = (TAc % h_) * h_ + TAc / h_;
    rowBase[d2] = (uint32_t)(iB * L_);
    rw0[d2] = ok && (iB - 1 >= 0);
    rw1[d2] = ok;
    rw2[d2] = ok && (iB + 1 < L_);
  }
  bool fastR = rw0[0] && rw1[0] && rw2[0] && rw0[1] && rw1[1] && rw2[1] &&
               rw0[2] && rw1[2] && rw2[2];

  float y[9];
  float mx = -3.0e38f;

  auto full_col = [&](int j, int jy) -> float {
    int jB0 = (jy >= 1) ? (j - h_) : (j + (L_ - h_ - 1));
    int jB1 = j;
    int jB2 = (jy <= h_ - 2) ? (j + h_) : (j - (L_ - h_ - 1));
    bool tb0 = (j > 0), tb2 = (j < L_ - 1);
    float s = 0.f;
    {
      uint32_t oc = rowBase[0] + (uint32_t)jB0;
      bool w0 = rw0[0] && tb0 && (jB0 > 0);
      bool w1 = rw1[0] && tb0;
      bool w2 = rw2[0] && tb0 && (jB0 < L_ - 1);
      float vm = h2f(Vb[w0 ? oc - (L_ + 1) : 0u]);
      float vc = h2f(Vb[w1 ? oc : 0u]);
      float vp = h2f(Vb[w2 ? oc + (L_ + 1) : 0u]);
      s += (w0 ? vm : 0.f) + (w1 ? vc : 0.f) + (w2 ? vp : 0.f);
    }
    {
      uint32_t oc = rowBase[1] + (uint32_t)jB1;
      bool w0 = rw0[1] && (jB1 > 0);
      bool w1 = rw1[1];
      bool w2 = rw2[1] && (jB1 < L_ - 1);
      float vm = h2f(Vb[w0 ? oc - (L_ + 1) : 0u]);
      float vc = h2f(Vb[w1 ? oc : 0u]);
      float vp = h2f(Vb[w2 ? oc + (L_ + 1) : 0u]);
      s += (w0 ? vm : 0.f) + (w1 ? vc : 0.f) + (w2 ? vp : 0.f);
    }
    {
      uint32_t oc = rowBase[2] + (uint32_t)jB2;
      bool w0 = rw0[2] && tb2 && (jB2 > 0);
      bool w1 = rw1[2] && tb2;
      bool w2 = rw2[2] && tb2 && (jB2 < L_ - 1);
      float vm = h2f(Vb[w0 ? oc - (L_ + 1) : 0u]);
      float vc = h2f(Vb[w1 ? oc : 0u]);
      float vp = h2f(Vb[w2 ? oc + (L_ + 1) : 0u]);
      s += (w0 ? vm : 0.f) + (w1 ? vc : 0.f) + (w2 ? vp : 0.f);
    }
    return s;
  };

  {
    int j = t;
    float zv = full_col(j, t / h_) * mmb[j] * SCALE_;
    y[0] = zv;
    mx = fmaxf(mx, zv);
  }
  if (fastR) {
#pragma unroll
    for (int cc = 1; cc <= 7; cc++) {
      int j = cc * 256 + t;
      float s = 0.f;
#pragma unroll
      for (int d2 = 0; d2 < 3; d2++) {
        uint32_t oc = rowBase[d2] + (uint32_t)(j + h_ * (d2 - 1));
        s += h2f(Vb[oc - (L_ + 1)]) + h2f(Vb[oc]) + h2f(Vb[oc + (L_ + 1)]);
      }
      float zv = s * mmb[j] * SCALE_;
      y[cc] = zv;
      mx = fmaxf(mx, zv);
    }
  } else {
#pragma unroll
    for (int cc = 1; cc <= 7; cc++) {
      int j = cc * 256 + t;
      float s = 0.f;
#pragma unroll
      for (int d2 = 0; d2 < 3; d2++) {
        uint32_t oc = rowBase[d2] + (uint32_t)(j + h_ * (d2 - 1));
        float vm = h2f(Vb[rw0[d2] ? oc - (L_ + 1) : 0u]);
        float vc = h2f(Vb[rw1[d2] ? oc : 0u]);
        float vp = h2f(Vb[rw2[d2] ? oc + (L_ + 1) : 0u]);
        s += (rw0[d2] ? vm : 0.f) + (rw1[d2] ? vc : 0.f) + (rw2[d2] ? vp : 0.f);
      }
      float zv = s * mmb[j] * SCALE_;
      y[cc] = zv;
      mx = fmaxf(mx, zv);
    }
  }
  {
    int j = 2048 + t;
    float zv = full_col(j, j / h_) * mmb[j] * SCALE_;
    y[8] = zv;
    mx = fmaxf(mx, zv);
  }

  int lane = t & 63, wid = t >> 6;
  __shared__ float wredm[4];
  __shared__ float wreds[4];
#pragma unroll
  for (int o = 32; o >= 1; o >>= 1) mx = fmaxf(mx, __shfl_xor(mx, o, 64));
  if (lane == 0) wredm[wid] = mx;
  __syncthreads();
  float MX = fmaxf(fmaxf(wredm[0], wredm[1]), fmaxf(wredm[2], wredm[3]));
  float sm = 0.f;
#pragma unroll
  for (int cc = 0; cc < 9; cc++) {
    y[cc] = __expf(y[cc] - MX);
    sm += y[cc];
  }
#pragma unroll
  for (int o = 32; o >= 1; o >>= 1) sm += __shfl_xor(sm, o, 64);
  if (lane == 0) wreds[wid] = sm;
  __syncthreads();
  float inv = 1.0f / (wreds[0] + wreds[1] + wreds[2] + wreds[3]);
#pragma unroll
  for (int cc = 0; cc < 9; cc++) {
    int j = cc * 256 + t;
    arow[j] = f2bf(y[cc] * inv * mmb[j]);
  }
}

// ---- deconv parity-gather scatter (P bf16, 4 channels/thread) -----------
__global__ __launch_bounds__(256) void k_scatter(const u16* __restrict__ P,
                                                 float* __restrict__ out) {
  int idx = blockIdx.x * 256 + threadIdx.x;   // over B*H*W*32
  int c4 = idx & 31;
  int r = idx >> 5;
  int xx = r % W_; r /= W_;
  int y = r % H_;
  int bz = r / H_;
  const u16* Pb = P + (size_t)bz * L_ * N9_;
  int yo[2], ya[2], ny = 0;
  if (y & 1) { yo[0] = y >> 1; ya[0] = 1; ny = 1; }
  else {
    yo[0] = y >> 1; ya[0] = 0; ny = 1;
    if (y >= 2) { yo[1] = (y >> 1) - 1; ya[1] = 2; ny = 2; }
  }
  int xo[2], xa[2], nx = 0;
  if (xx & 1) { xo[0] = xx >> 1; xa[0] = 1; nx = 1; }
  else {
    xo[0] = xx >> 1; xa[0] = 0; nx = 1;
    if (xx >= 2) { xo[1] = (xx >> 1) - 1; xa[1] = 2; nx = 2; }
  }
  float s[4] = {0.f, 0.f, 0.f, 0.f};
  for (int i = 0; i < ny; i++)
    for (int j = 0; j < nx; j++) {
      size_t off = (size_t)(yo[i] * h_ + xo[j]) * N9_ + (ya[i] * 3 + xa[j]) * C_ + 4 * c4;
      ushort4v w = *(const ushort4v*)(Pb + off);
#pragma unroll
      for (int k = 0; k < 4; k++) s[k] += bf2f(w[k]);
    }
  f32x4 o;
#pragma unroll
  for (int k = 0; k < 4; k++) o[k] = 0.25f * s[k];
  *(f32x4*)(out + ((size_t)bz * H_ + y) * (size_t)W_ * C_ + (size_t)xx * C_ + 4 * c4) = o;
}

}  // namespace

extern "C" void kernel_launch(void* const* d_in, const int* in_sizes, int n_in,
                              void* d_out, int out_size, void* d_ws, size_t ws_size,
                              hipStream_t stream) {
  (void)in_sizes; (void)n_in; (void)out_size;
  const float* x = (const float*)d_in[0];
  const float* mask = (const float*)d_in[1];
  float* out = (float*)d_out;
  char* ws = (char*)d_ws;

  const size_t szF3 = (size_t)B_ * L_ * K3_ * sizeof(u16);
  const size_t szSm = (size_t)B_ * L_ * sizeof(float);
  const size_t off_F3a = 0;
  const size_t off_F3b = off_F3a + szF3;
  const size_t off_S = off_F3b + szF3;
  const size_t off_md = off_S + szSm;
  const size_t off_mm = off_md + szSm;
  const size_t off_nv = off_mm + szSm;
  const size_t off_fixed_end = off_nv + szSm;

  const size_t perXp = (size_t)N9_ * L_ * sizeof(u16);   // 5.3 MB
  const size_t perU = (size_t)L_ * L_ * sizeof(u16);     // 10.6 MB (fp16)
  const size_t perV = (size_t)L_ * L_ * sizeof(u16);     // 10.6 MB (fp16)
  int G = 4;
  while (G > 1 && off_fixed_end + (size_t)G * (perXp + perU + perV) > ws_size) G >>= 1;

  const size_t off_XpT = off_fixed_end;
  const size_t off_U = off_XpT + (size_t)G * perXp;
  const size_t off_V = off_U + (size_t)G * perU;

  u16* F3a = (u16*)(ws + off_F3a);
  u16* F3b = (u16*)(ws + off_F3b);
  float* S = (float*)(ws + off_S);
  float* md = (float*)(ws + off_md);
  float* mm = (float*)(ws + off_mm);
  float* nv = (float*)(ws + off_nv);
  u16* XpT = (u16*)(ws + off_XpT);
  u16* U = (u16*)(ws + off_U);
  u16* V = (u16*)(ws + off_V);
  u16* Abuf = (u16*)(ws + off_U);   // alias U (U dead after patchsum)
  u16* Pbuf = (u16*)(ws + off_V);   // alias V (V dead after fsm)

  k_down<<<dim3(B_ * L_), dim3(C_), 0, stream>>>(x, F3a, F3b, S);
  k_mask<<<dim3((B_ * L_) / 256), dim3(256), 0, stream>>>(mask, md);
  k_mmnorm<<<dim3((B_ * L_) / 256), dim3(256), 0, stream>>>(S, md, mm, nv);

  for (int sb = 0; sb < B_; sb += G) {
    const float* xs = x + (size_t)sb * H_ * W_ * C_;
    k_xpack<<<dim3(L_ / 32, N9_ / 64, G), dim3(256), 0, stream>>>(xs, XpT);
    // Gram (symmetric): 171 upper-triangle tiles of the 18x18 grid
    gemm_bt<OUT_F16, true><<<dim3(171, 1, G), dim3(256), 0, stream>>>(
        F3a + (size_t)sb * L_ * K3_, F3b + (size_t)sb * L_ * K3_, (void*)U,
        L_, K3_, (size_t)L_ * K3_, (size_t)L_ * K3_, (size_t)L_ * L_);
    k_patchsum<<<dim3((L_ * L_) / (256 * 8), 1, G), dim3(256), 0, stream>>>(U, V, nv, sb);
    k_fsm<<<dim3(L_, G), dim3(256), 0, stream>>>(V, mm, Abuf, sb);
    // Apply: 144x144 tiles, BK=32 -> (8, 16, 4) = 512 blocks = exactly 2/CU
    gemm_ap144<<<dim3(N9_ / 144, L_ / 144, G), dim3(576), 0, stream>>>(
        Abuf, XpT, Pbuf, N9_, L_,
        (size_t)L_ * L_, (size_t)N9_ * L_, (size_t)L_ * N9_);
    k_scatter<<<dim3((G * H_ * W_ * C_ / 4) / 256), dim3(256), 0, stream>>>(
        Pbuf, out + (size_t)sb * H_ * W_ * C_);
  }
}